// Round 1
// baseline (631.849 us; speedup 1.0000x reference)
//
#include <hip/hip_runtime.h>
#include <math.h>

#define Bn 8
#define Hd 128
#define Ld 8192
#define Pd 256
#define LC 32
#define NC 256  // Ld / LC

// ---------------- kernel 0: transposes into workspace ----------------
__global__ __launch_bounds__(256) void k_prep(
    const float* __restrict__ Bre, const float* __restrict__ Bim,
    const float* __restrict__ Cre, const float* __restrict__ Cim,
    const float* __restrict__ Dm,
    float2* __restrict__ BT, float2* __restrict__ CT, float* __restrict__ DT) {
  int i = blockIdx.x * 256 + threadIdx.x;
  if (i < Hd * Pd) {
    int h = i / Pd, p = i % Pd;  // BT[h][p] = B_bar[p][h]
    BT[i] = make_float2(Bre[p * Hd + h], Bim[p * Hd + h]);
    int p2 = i / Hd, h2 = i % Hd;  // CT[p][h] = C[h][p]
    CT[i] = make_float2(Cre[h2 * Pd + p2], Cim[h2 * Pd + p2]);
  }
  if (i < Hd * Hd) {
    int r = i / Hd, s = i % Hd;  // DT[h'][h] = D[h][h']
    DT[i] = Dm[s * Hd + r];
  }
}

// ---------------- kernel 1: per-chunk state contribution E ----------------
// E[b][c][p] = sum_{j=0..31} a^{32-j} Bu[b,p,32c+j]
__global__ __launch_bounds__(256) void k_chunk(
    const float* __restrict__ u, const float* __restrict__ lre,
    const float* __restrict__ lim, const float2* __restrict__ BT,
    float2* __restrict__ E) {
  int bc = blockIdx.x;
  int b = bc >> 8, c = bc & 255;
  __shared__ __align__(16) float u_s[Hd * LC];  // 16 KB

  const float* ub = u + (size_t)b * Hd * Ld + c * LC;
  int t = threadIdx.x;
  {
    int h = t >> 1, j0 = (t & 1) * 16;
    const float4* src = (const float4*)(ub + (size_t)h * Ld + j0);
    float4* dst = (float4*)(u_s + h * LC + j0);
    dst[0] = src[0]; dst[1] = src[1]; dst[2] = src[2]; dst[3] = src[3];
  }
  __syncthreads();

  int p = t;
  float ar[LC], ai[LC];
#pragma unroll
  for (int j = 0; j < LC; ++j) { ar[j] = 0.f; ai[j] = 0.f; }

#pragma unroll 2
  for (int h = 0; h < Hd; ++h) {
    float2 bb = BT[(h << 8) | p];
    const float4* ur = (const float4*)(u_s + h * LC);
#pragma unroll
    for (int q = 0; q < 8; ++q) {
      float4 uv = ur[q];
      ar[4 * q + 0] += bb.x * uv.x;  ai[4 * q + 0] += bb.y * uv.x;
      ar[4 * q + 1] += bb.x * uv.y;  ai[4 * q + 1] += bb.y * uv.y;
      ar[4 * q + 2] += bb.x * uv.z;  ai[4 * q + 2] += bb.y * uv.z;
      ar[4 * q + 3] += bb.x * uv.w;  ai[4 * q + 3] += bb.y * uv.w;
    }
  }

  // Horner: e = sum_j a^{31-j} Bu_j ; E = a * e
  float ax = lre[p], ay = lim[p];
  float ex = 0.f, ey = 0.f;
#pragma unroll
  for (int j = 0; j < LC; ++j) {
    float nx = ax * ex - ay * ey + ar[j];
    float ny = ax * ey + ay * ex + ai[j];
    ex = nx; ey = ny;
  }
  float fx = ax * ex - ay * ey;
  float fy = ax * ey + ay * ex;
  E[(size_t)bc * Pd + p] = make_float2(fx, fy);
}

// ---------------- kernel 2: in-place prefix scan over chunks ----------------
// After this, E[b][c][p] holds the INCOMING state x_{32c-1} for chunk c.
__global__ __launch_bounds__(256) void k_scan(const float* __restrict__ lre,
                                              const float* __restrict__ lim,
                                              float2* __restrict__ E) {
  int g = blockIdx.x * 256 + threadIdx.x;  // 0..2047
  int b = g >> 8, p = g & 255;
  float ax = lre[p], ay = lim[p];
  // a^32 by 5 squarings
  float sx = ax, sy = ay;
#pragma unroll
  for (int k = 0; k < 5; ++k) {
    float nx = sx * sx - sy * sy;
    float ny = 2.f * sx * sy;
    sx = nx; sy = ny;
  }
  float xr = 0.f, xi = 0.f;
  for (int c = 0; c < NC; ++c) {
    size_t idx = ((size_t)(b * NC + c)) * Pd + p;
    float2 e = E[idx];
    E[idx] = make_float2(xr, xi);
    float nx = sx * xr - sy * xi + e.x;
    float ny = sx * xi + sy * xr + e.y;
    xr = nx; xi = ny;
  }
}

// ---------------- kernel 3: main fused kernel ----------------
__global__ __launch_bounds__(256) void k_main(
    const float* __restrict__ u, const float* __restrict__ lre,
    const float* __restrict__ lim, const float2* __restrict__ BT,
    const float2* __restrict__ CT, const float* __restrict__ DT,
    const float2* __restrict__ E, float* __restrict__ out) {
  int bc = blockIdx.x;
  int b = bc >> 8, c = bc & 255;

  // xs planes [32][257] fp32, padded; u_s (16 KB) aliases the front.
  __shared__ __align__(16) float smem[2 * LC * 257];  // 65,792 B
  float* xs_re = smem;
  float* xs_im = smem + LC * 257;
  float* u_s = smem;  // alias: only live during phase A

  const float* ub = u + (size_t)b * Hd * Ld + c * LC;
  int t = threadIdx.x;
  {
    int h = t >> 1, j0 = (t & 1) * 16;
    const float4* src = (const float4*)(ub + (size_t)h * Ld + j0);
    float4* dst = (float4*)(u_s + h * LC + j0);
    dst[0] = src[0]; dst[1] = src[1]; dst[2] = src[2]; dst[3] = src[3];
  }
  __syncthreads();

  // ---- phase A: Bu[p][0..31] in registers ----
  int p = t;
  float ar[LC], ai[LC];
#pragma unroll
  for (int j = 0; j < LC; ++j) { ar[j] = 0.f; ai[j] = 0.f; }

#pragma unroll 2
  for (int h = 0; h < Hd; ++h) {
    float2 bb = BT[(h << 8) | p];
    const float4* ur = (const float4*)(u_s + h * LC);
#pragma unroll
    for (int q = 0; q < 8; ++q) {
      float4 uv = ur[q];
      ar[4 * q + 0] += bb.x * uv.x;  ai[4 * q + 0] += bb.y * uv.x;
      ar[4 * q + 1] += bb.x * uv.y;  ai[4 * q + 1] += bb.y * uv.y;
      ar[4 * q + 2] += bb.x * uv.z;  ai[4 * q + 2] += bb.y * uv.z;
      ar[4 * q + 3] += bb.x * uv.w;  ai[4 * q + 3] += bb.y * uv.w;
    }
  }
  __syncthreads();  // everyone done reading u_s before xs overwrites it

  // ---- phase B: seeded local scan, write xs to LDS ----
  {
    float ax = lre[p], ay = lim[p];
    float2 s0 = E[(size_t)bc * Pd + p];
    float xr = s0.x, xi = s0.y;
#pragma unroll
    for (int j = 0; j < LC; ++j) {
      float sr = xr + ar[j], si = xi + ai[j];
      xr = ax * sr - ay * si;
      xi = ax * si + ay * sr;
      xs_re[j * 257 + p] = xr;
      xs_im[j * 257 + p] = xi;
    }
  }
  __syncthreads();

  // ---- phase C: y = Re(C xs) + D u, GELU, store ----
  int jp = t & 15, hg = t >> 4;
  int j0 = 2 * jp, h0 = hg * 8;
  float y0[8], y1[8];
#pragma unroll
  for (int h = 0; h < 8; ++h) { y0[h] = 0.f; y1[h] = 0.f; }

#pragma unroll 2
  for (int p2 = 0; p2 < Pd; ++p2) {
    float xr0 = xs_re[j0 * 257 + p2];
    float xi0 = xs_im[j0 * 257 + p2];
    float xr1 = xs_re[(j0 + 1) * 257 + p2];
    float xi1 = xs_im[(j0 + 1) * 257 + p2];
    const float4* crow = (const float4*)(CT + (size_t)p2 * Hd + h0);
#pragma unroll
    for (int q = 0; q < 4; ++q) {
      float4 cc = crow[q];  // {re(h),im(h),re(h+1),im(h+1)}
      y0[2 * q + 0] += cc.x * xr0 - cc.y * xi0;
      y0[2 * q + 1] += cc.z * xr0 - cc.w * xi0;
      y1[2 * q + 0] += cc.x * xr1 - cc.y * xi1;
      y1[2 * q + 1] += cc.z * xr1 - cc.w * xi1;
    }
  }

  // D @ u part: u re-read from global (u_s was overwritten by xs)
  const float* ubj = u + (size_t)b * Hd * Ld + c * LC + j0;
#pragma unroll 4
  for (int hp = 0; hp < Hd; ++hp) {
    float2 uu = *(const float2*)(ubj + (size_t)hp * Ld);
    const float4* drow = (const float4*)(DT + hp * Hd + h0);
    float4 d0 = drow[0], d1 = drow[1];
    y0[0] += d0.x * uu.x;  y1[0] += d0.x * uu.y;
    y0[1] += d0.y * uu.x;  y1[1] += d0.y * uu.y;
    y0[2] += d0.z * uu.x;  y1[2] += d0.z * uu.y;
    y0[3] += d0.w * uu.x;  y1[3] += d0.w * uu.y;
    y0[4] += d1.x * uu.x;  y1[4] += d1.x * uu.y;
    y0[5] += d1.y * uu.x;  y1[5] += d1.y * uu.y;
    y0[6] += d1.z * uu.x;  y1[6] += d1.z * uu.y;
    y0[7] += d1.w * uu.x;  y1[7] += d1.w * uu.y;
  }

  const float inv_sqrt2 = 0.70710678118654752f;
  float* ob = out + (size_t)b * Hd * Ld + c * LC + j0;
#pragma unroll
  for (int h = 0; h < 8; ++h) {
    float v0 = y0[h], v1 = y1[h];
    float g0 = 0.5f * v0 * (1.0f + erff(v0 * inv_sqrt2));
    float g1 = 0.5f * v1 * (1.0f + erff(v1 * inv_sqrt2));
    *(float2*)(ob + (size_t)(h0 + h) * Ld) = make_float2(g0, g1);
  }
}

// ---------------- launch ----------------
extern "C" void kernel_launch(void* const* d_in, const int* in_sizes, int n_in,
                              void* d_out, int out_size, void* d_ws, size_t ws_size,
                              hipStream_t stream) {
  const float* u   = (const float*)d_in[0];
  const float* lre = (const float*)d_in[1];
  const float* lim = (const float*)d_in[2];
  const float* Bre = (const float*)d_in[3];
  const float* Bim = (const float*)d_in[4];
  const float* Cre = (const float*)d_in[5];
  const float* Cim = (const float*)d_in[6];
  const float* Dm  = (const float*)d_in[7];
  float* out = (float*)d_out;

  char* ws = (char*)d_ws;
  float2* BT = (float2*)(ws);                     // 256 KB
  float2* CT = (float2*)(ws + 256 * 1024);        // 256 KB
  float*  DT = (float*)(ws + 512 * 1024);         // 64 KB
  float2* E  = (float2*)(ws + 1024 * 1024);       // 4 MB  (B*NC*P float2)

  k_prep<<<(Hd * Pd + 255) / 256, 256, 0, stream>>>(Bre, Bim, Cre, Cim, Dm, BT, CT, DT);
  k_chunk<<<Bn * NC, 256, 0, stream>>>(u, lre, lim, BT, E);
  k_scan<<<(Bn * Pd) / 256, 256, 0, stream>>>(lre, lim, E);
  k_main<<<Bn * NC, 256, 0, stream>>>(u, lre, lim, BT, CT, DT, E, out);
}

// Round 2
// 165.580 us; speedup vs baseline: 3.8160x; 3.8160x over previous
//
#include <hip/hip_runtime.h>
#include <math.h>

#define Bn 8
#define Hd 128
#define Ld 8192
#define Pd 256
#define LC 32
#define NC 256  // Ld / LC

typedef __attribute__((ext_vector_type(8))) short bf16x8;
typedef __attribute__((ext_vector_type(4))) float f32x4;
#define MFMA16(a, b, c) __builtin_amdgcn_mfma_f32_16x16x32_bf16(a, b, c, 0, 0, 0)

__device__ __forceinline__ unsigned short f2bf(float f) {
  unsigned u = __float_as_uint(f);
  u = u + 0x7fffu + ((u >> 16) & 1u);  // round-to-nearest-even
  return (unsigned short)(u >> 16);
}
__device__ __forceinline__ unsigned pack2(float a, float b) {
  return (unsigned)f2bf(a) | ((unsigned)f2bf(b) << 16);
}
__device__ __forceinline__ float bflo(unsigned v) { return __uint_as_float(v << 16); }
__device__ __forceinline__ float bfhi(unsigned v) { return __uint_as_float(v & 0xffff0000u); }

// ---------------- kernel 0: repack B,C,D into MFMA A-fragment order ----------------
// A-frag layout (16x16x32): lane holds A[m = mt*16 + (lane&15)][k = ks*32 + (lane>>4)*8 + e]
// Bfr/Bfi: 64 tiles (ks0..3 x mt0..15).  Cf: 128 tiles (ks0..15 x mt0..7) over K'=512
// interleaved (even k' -> Cre[o][p], odd k' -> -Cim[o][p], p = k'>>1).  Df: 32 tiles.
__global__ void k_prep(const float* __restrict__ Bre, const float* __restrict__ Bim,
                       const float* __restrict__ Cre, const float* __restrict__ Cim,
                       const float* __restrict__ Dm,
                       bf16x8* __restrict__ Bfr, bf16x8* __restrict__ Bfi,
                       bf16x8* __restrict__ Cf, bf16x8* __restrict__ Df) {
  int tid = blockIdx.x * 256 + threadIdx.x;
  int lane = tid & 63, slot = tid >> 6;
  int q = lane >> 4, ln = lane & 15;
  if (slot < 64) {  // B tables
    int ks = slot >> 4, mt = slot & 15;
    int p = mt * 16 + ln;
    bf16x8 vr, vi;
#pragma unroll
    for (int e = 0; e < 8; ++e) {
      int h = ks * 32 + q * 8 + e;
      vr[e] = (short)f2bf(Bre[p * Hd + h]);
      vi[e] = (short)f2bf(Bim[p * Hd + h]);
    }
    Bfr[slot * 64 + lane] = vr;
    Bfi[slot * 64 + lane] = vi;
  } else if (slot < 64 + 128) {  // C table, K' = 512 interleaved
    int s2 = slot - 64;
    int ks = s2 >> 3, mt = s2 & 7;
    int o = mt * 16 + ln;
    bf16x8 v;
#pragma unroll
    for (int e = 0; e < 8; ++e) {
      int kp = ks * 32 + q * 8 + e;
      int p = kp >> 1;
      float val = (kp & 1) ? -Cim[o * Pd + p] : Cre[o * Pd + p];
      v[e] = (short)f2bf(val);
    }
    Cf[s2 * 64 + lane] = v;
  } else if (slot < 64 + 128 + 32) {  // D table
    int s3 = slot - 192;
    int ks = s3 >> 3, mt = s3 & 7;
    int o = mt * 16 + ln;
    bf16x8 v;
#pragma unroll
    for (int e = 0; e < 8; ++e) {
      int h = ks * 32 + q * 8 + e;
      v[e] = (short)f2bf(Dm[o * Hd + h]);
    }
    Df[s3 * 64 + lane] = v;
  }
}

// ---- shared helpers for k_chunk / k_main ----
// u_s: 32 rows (j) x 128 bf16 (h), 256 B/row, XOR-swizzled 16B granules:
//   granule g of row j stored at g ^ (j&7)  -> conflict-free b128 B-frag reads.
__device__ __forceinline__ void stage_u(const float* __restrict__ ub, unsigned* us32, int t) {
  int lane = t & 63, w = t >> 6;
  int j0 = 4 * (lane & 7);
  int h2 = 16 * w + 2 * (lane >> 3);  // even, 0..62 (+64 for second half)
  const float* r0 = ub + (size_t)h2 * Ld + j0;
  float4 a0 = *(const float4*)r0;
  float4 a1 = *(const float4*)(r0 + Ld);
  const float* r2 = r0 + (size_t)64 * Ld;
  float4 b0 = *(const float4*)r2;
  float4 b1 = *(const float4*)(r2 + Ld);
  float ta0[4] = {a0.x, a0.y, a0.z, a0.w};
  float ta1[4] = {a1.x, a1.y, a1.z, a1.w};
  float tb0[4] = {b0.x, b0.y, b0.z, b0.w};
  float tb1[4] = {b1.x, b1.y, b1.z, b1.w};
#pragma unroll
  for (int i = 0; i < 4; ++i) {
    int j = j0 + i;
    int g1 = (h2 >> 3) ^ (j & 7);
    us32[(j * 256 + (g1 << 4) + ((2 * h2) & 15)) >> 2] = pack2(ta0[i], ta1[i]);
    int hb = h2 + 64;
    int g2 = (hb >> 3) ^ (j & 7);
    us32[(j * 256 + (g2 << 4) + ((2 * hb) & 15)) >> 2] = pack2(tb0[i], tb1[i]);
  }
}

// Bu = B_bar @ u_tile via MFMA; writes packed bf16 (re,im) to bu32[p*35 + j]
__device__ __forceinline__ void compute_bu(const unsigned* us32,
                                           const bf16x8* __restrict__ Bfr,
                                           const bf16x8* __restrict__ Bfi,
                                           unsigned* bu32, int t) {
  int lane = t & 63, w = t >> 6, q = lane >> 4, ln = lane & 15;
  f32x4 zz = {0.f, 0.f, 0.f, 0.f};
  f32x4 aR[4][2], aI[4][2];
#pragma unroll
  for (int mt = 0; mt < 4; ++mt)
#pragma unroll
    for (int n = 0; n < 2; ++n) { aR[mt][n] = zz; aI[mt][n] = zz; }

#pragma unroll
  for (int ks = 0; ks < 4; ++ks) {
    bf16x8 ubf[2];
#pragma unroll
    for (int n = 0; n < 2; ++n) {
      int j = 16 * n + ln;
      int g = (4 * ks + q) ^ (j & 7);
      ubf[n] = *(const bf16x8*)((const char*)us32 + j * 256 + g * 16);
    }
#pragma unroll
    for (int mt = 0; mt < 4; ++mt) {
      int tI = ks * 16 + w * 4 + mt;
      bf16x8 ar = Bfr[tI * 64 + lane];
      bf16x8 ai = Bfi[tI * 64 + lane];
#pragma unroll
      for (int n = 0; n < 2; ++n) {
        aR[mt][n] = MFMA16(ar, ubf[n], aR[mt][n]);
        aI[mt][n] = MFMA16(ai, ubf[n], aI[mt][n]);
      }
    }
  }
  // D-frag: row p = w*64 + mt*16 + q*4 + r, col j = 16n + ln
#pragma unroll
  for (int mt = 0; mt < 4; ++mt)
#pragma unroll
    for (int n = 0; n < 2; ++n)
#pragma unroll
      for (int r = 0; r < 4; ++r) {
        int p = w * 64 + mt * 16 + q * 4 + r;
        int j = 16 * n + ln;
        bu32[p * 35 + j] = pack2(aR[mt][n][r], aI[mt][n][r]);
      }
}

// ---------------- kernel 1: per-chunk state contribution E ----------------
__global__ __launch_bounds__(256, 3) void k_chunk(
    const float* __restrict__ u, const float* __restrict__ lre,
    const float* __restrict__ lim, const bf16x8* __restrict__ Bfr,
    const bf16x8* __restrict__ Bfi, float2* __restrict__ E) {
  int bc = blockIdx.x;
  int b = bc >> 8, c = bc & 255;
  __shared__ __align__(16) unsigned char smem[8192 + 35840];
  unsigned* us32 = (unsigned*)smem;
  unsigned* bu32 = (unsigned*)(smem + 8192);
  int t = threadIdx.x;

  stage_u(u + (size_t)b * Hd * Ld + c * LC, us32, t);
  __syncthreads();
  compute_bu(us32, Bfr, Bfi, bu32, t);
  __syncthreads();

  int p = t;
  float ax = lre[p], ay = lim[p];
  float xr = 0.f, xi = 0.f;
#pragma unroll
  for (int j = 0; j < LC; ++j) {
    unsigned v = bu32[p * 35 + j];
    float sr = xr + bflo(v), si = xi + bfhi(v);
    xr = ax * sr - ay * si;
    xi = ax * si + ay * sr;
  }
  E[(size_t)bc * Pd + p] = make_float2(xr, xi);
}

// ---------------- kernel 2: in-place prefix scan over chunks (fp32) ----------------
__global__ __launch_bounds__(256) void k_scan(const float* __restrict__ lre,
                                              const float* __restrict__ lim,
                                              float2* __restrict__ E) {
  int g = blockIdx.x * 256 + threadIdx.x;  // 0..2047
  int b = g >> 8, p = g & 255;
  float ax = lre[p], ay = lim[p];
  float sx = ax, sy = ay;
#pragma unroll
  for (int k = 0; k < 5; ++k) {  // a^32
    float nx = sx * sx - sy * sy;
    float ny = 2.f * sx * sy;
    sx = nx; sy = ny;
  }
  float xr = 0.f, xi = 0.f;
  for (int c = 0; c < NC; ++c) {
    size_t idx = ((size_t)(b * NC + c)) * Pd + p;
    float2 e = E[idx];
    E[idx] = make_float2(xr, xi);
    float nx = sx * xr - sy * xi + e.x;
    float ny = sx * xi + sy * xr + e.y;
    xr = nx; xi = ny;
  }
}

// ---------------- kernel 3: main fused kernel ----------------
__global__ __launch_bounds__(256, 3) void k_main(
    const float* __restrict__ u, const float* __restrict__ lre,
    const float* __restrict__ lim, const bf16x8* __restrict__ Bfr,
    const bf16x8* __restrict__ Bfi, const bf16x8* __restrict__ Cf,
    const bf16x8* __restrict__ Df, const float2* __restrict__ E,
    float* __restrict__ out) {
  int bc = blockIdx.x;
  int b = bc >> 8, c = bc & 255;
  __shared__ __align__(16) unsigned char smem[8192 + 35840];
  unsigned* us32 = (unsigned*)smem;
  unsigned* bu32 = (unsigned*)(smem + 8192);
  unsigned* xs32 = bu32;  // alias: bu dead after scan reads
  int t = threadIdx.x;
  int lane = t & 63, w = t >> 6, q = lane >> 4, ln = lane & 15;

  stage_u(u + (size_t)b * Hd * Ld + c * LC, us32, t);
  __syncthreads();
  compute_bu(us32, Bfr, Bfi, bu32, t);
  __syncthreads();

  // ---- scan: thread p owns row p; buffer bu row in regs so xs can alias ----
  int p = t;
  unsigned v[LC];
#pragma unroll
  for (int j = 0; j < LC; ++j) v[j] = bu32[p * 35 + j];
  float2 xin = E[(size_t)bc * Pd + p];
  __syncthreads();  // all bu reads done before xs overwrites

  {
    float ax = lre[p], ay = lim[p];
    float xr = xin.x, xi = xin.y;
#pragma unroll
    for (int j = 0; j < LC; ++j) {
      float sr = xr + bflo(v[j]), si = xi + bfhi(v[j]);
      xr = ax * sr - ay * si;
      xi = ax * si + ay * sr;
      // xs row j: 1024 B, granule (p>>2)^(j&7), packed (re,im) b32 at uint-col p
      xs32[j * 256 + ((((p >> 2) ^ (j & 7)) << 2) + (p & 3))] = pack2(xr, xi);
    }
  }
  __syncthreads();

  // ---- projection: y = [Cre | -Cim] @ xs_interleaved + D @ u ----
  f32x4 zz = {0.f, 0.f, 0.f, 0.f};
  f32x4 acc[2][2] = {{zz, zz}, {zz, zz}};
#pragma unroll
  for (int ks = 0; ks < 16; ++ks) {
    bf16x8 xb[2];
#pragma unroll
    for (int n = 0; n < 2; ++n) {
      int j = 16 * n + ln;
      int g = (4 * ks + q) ^ (j & 7);
      xb[n] = *(const bf16x8*)((const char*)xs32 + j * 1024 + g * 16);
    }
#pragma unroll
    for (int mt = 0; mt < 2; ++mt) {
      bf16x8 cf = Cf[(ks * 8 + w * 2 + mt) * 64 + lane];
#pragma unroll
      for (int n = 0; n < 2; ++n) acc[mt][n] = MFMA16(cf, xb[n], acc[mt][n]);
    }
  }
#pragma unroll
  for (int ks = 0; ks < 4; ++ks) {
    bf16x8 ubf[2];
#pragma unroll
    for (int n = 0; n < 2; ++n) {
      int j = 16 * n + ln;
      int g = (4 * ks + q) ^ (j & 7);
      ubf[n] = *(const bf16x8*)((const char*)us32 + j * 256 + g * 16);
    }
#pragma unroll
    for (int mt = 0; mt < 2; ++mt) {
      bf16x8 df = Df[(ks * 8 + w * 2 + mt) * 64 + lane];
#pragma unroll
      for (int n = 0; n < 2; ++n) acc[mt][n] = MFMA16(df, ubf[n], acc[mt][n]);
    }
  }

  // ---- GELU + store ----
  const float inv_sqrt2 = 0.70710678118654752f;
#pragma unroll
  for (int mt = 0; mt < 2; ++mt)
#pragma unroll
    for (int n = 0; n < 2; ++n)
#pragma unroll
      for (int r = 0; r < 4; ++r) {
        int o = w * 32 + mt * 16 + q * 4 + r;
        int l = c * LC + 16 * n + ln;
        float vy = acc[mt][n][r];
        float gy = 0.5f * vy * (1.0f + erff(vy * inv_sqrt2));
        out[((size_t)(b * Hd + o)) * Ld + l] = gy;
      }
}

// ---------------- launch ----------------
extern "C" void kernel_launch(void* const* d_in, const int* in_sizes, int n_in,
                              void* d_out, int out_size, void* d_ws, size_t ws_size,
                              hipStream_t stream) {
  const float* u   = (const float*)d_in[0];
  const float* lre = (const float*)d_in[1];
  const float* lim = (const float*)d_in[2];
  const float* Bre = (const float*)d_in[3];
  const float* Bim = (const float*)d_in[4];
  const float* Cre = (const float*)d_in[5];
  const float* Cim = (const float*)d_in[6];
  const float* Dm  = (const float*)d_in[7];
  float* out = (float*)d_out;

  char* ws = (char*)d_ws;
  bf16x8* Bfr = (bf16x8*)(ws);                 // 64 KB
  bf16x8* Bfi = (bf16x8*)(ws + 65536);         // 64 KB
  bf16x8* Cf  = (bf16x8*)(ws + 131072);        // 128 KB
  bf16x8* Df  = (bf16x8*)(ws + 262144);        // 32 KB
  float2* E   = (float2*)(ws + (1 << 20));     // 4 MB

  k_prep<<<56, 256, 0, stream>>>(Bre, Bim, Cre, Cim, Dm, Bfr, Bfi, Cf, Df);
  k_chunk<<<Bn * NC, 256, 0, stream>>>(u, lre, lim, Bfr, Bfi, E);
  k_scan<<<(Bn * Pd) / 256, 256, 0, stream>>>(lre, lim, E);
  k_main<<<Bn * NC, 256, 0, stream>>>(u, lre, lim, Bfr, Bfi, Cf, Df, E, out);
}

// Round 3
// 152.987 us; speedup vs baseline: 4.1301x; 1.0823x over previous
//
#include <hip/hip_runtime.h>
#include <math.h>

#define Bn 8
#define Hd 128
#define Ld 8192
#define Pd 256
#define LC 32
#define NC 256  // Ld / LC

typedef __attribute__((ext_vector_type(8))) short bf16x8;
typedef __attribute__((ext_vector_type(4))) float f32x4;
#define MFMA16(a, b, c) __builtin_amdgcn_mfma_f32_16x16x32_bf16(a, b, c, 0, 0, 0)

__device__ __forceinline__ unsigned short f2bf(float f) {
  unsigned u = __float_as_uint(f);
  u = u + 0x7fffu + ((u >> 16) & 1u);  // round-to-nearest-even
  return (unsigned short)(u >> 16);
}

#if __has_builtin(__builtin_amdgcn_cvt_pk_bf16_f32)
typedef __attribute__((ext_vector_type(2))) __bf16 v2bf_t;
__device__ __forceinline__ unsigned pack2(float a, float b) {
  v2bf_t r = __builtin_amdgcn_cvt_pk_bf16_f32(a, b);  // low = a, high = b
  unsigned u;
  __builtin_memcpy(&u, &r, 4);
  return u;
}
#else
__device__ __forceinline__ unsigned pack2(float a, float b) {
  return (unsigned)f2bf(a) | ((unsigned)f2bf(b) << 16);
}
#endif

__device__ __forceinline__ float bflo(unsigned v) { return __uint_as_float(v << 16); }
__device__ __forceinline__ float bfhi(unsigned v) { return __uint_as_float(v & 0xffff0000u); }

// bu column swizzle: bijective 5-bit perm of p&31 -> 2-way-max banks on both
// C-frag writes (lanes vary q,ln) and per-p scan reads (lanes vary p).
__device__ __forceinline__ int bperm(int p) {
  return ((p & 4) << 2) | ((p & 16) >> 1) | ((p & 8) >> 1) | (p & 3);
}

// ---------------- kernel 0: repack B,C,D into MFMA A-fragment order ----------------
__global__ void k_prep(const float* __restrict__ Bre, const float* __restrict__ Bim,
                       const float* __restrict__ Cre, const float* __restrict__ Cim,
                       const float* __restrict__ Dm,
                       bf16x8* __restrict__ Bfr, bf16x8* __restrict__ Bfi,
                       bf16x8* __restrict__ Cf, bf16x8* __restrict__ Df) {
  int tid = blockIdx.x * 256 + threadIdx.x;
  int lane = tid & 63, slot = tid >> 6;
  int q = lane >> 4, ln = lane & 15;
  if (slot < 64) {  // B tables
    int ks = slot >> 4, mt = slot & 15;
    int p = mt * 16 + ln;
    bf16x8 vr, vi;
#pragma unroll
    for (int e = 0; e < 8; ++e) {
      int h = ks * 32 + q * 8 + e;
      vr[e] = (short)f2bf(Bre[p * Hd + h]);
      vi[e] = (short)f2bf(Bim[p * Hd + h]);
    }
    Bfr[slot * 64 + lane] = vr;
    Bfi[slot * 64 + lane] = vi;
  } else if (slot < 64 + 128) {  // C table, K' = 512 interleaved (re, -im)
    int s2 = slot - 64;
    int ks = s2 >> 3, mt = s2 & 7;
    int o = mt * 16 + ln;
    bf16x8 v;
#pragma unroll
    for (int e = 0; e < 8; ++e) {
      int kp = ks * 32 + q * 8 + e;
      int p = kp >> 1;
      float val = (kp & 1) ? -Cim[o * Pd + p] : Cre[o * Pd + p];
      v[e] = (short)f2bf(val);
    }
    Cf[s2 * 64 + lane] = v;
  } else if (slot < 64 + 128 + 32) {  // D table
    int s3 = slot - 192;
    int ks = s3 >> 3, mt = s3 & 7;
    int o = mt * 16 + ln;
    bf16x8 v;
#pragma unroll
    for (int e = 0; e < 8; ++e) {
      int h = ks * 32 + q * 8 + e;
      v[e] = (short)f2bf(Dm[o * Hd + h]);
    }
    Df[s3 * 64 + lane] = v;
  }
}

// ---- u staging: 32 rows (j) x 128 bf16 (h), 256 B/row, XOR-swizzled 16B granules
__device__ __forceinline__ void stage_u(const float* __restrict__ ub, unsigned* us32, int t) {
  int lane = t & 63, w = t >> 6;
  int j0 = 4 * (lane & 7);
  int h2 = 16 * w + 2 * (lane >> 3);
  const float* r0 = ub + (size_t)h2 * Ld + j0;
  float4 a0 = *(const float4*)r0;
  float4 a1 = *(const float4*)(r0 + Ld);
  const float* r2 = r0 + (size_t)64 * Ld;
  float4 b0 = *(const float4*)r2;
  float4 b1 = *(const float4*)(r2 + Ld);
  float ta0[4] = {a0.x, a0.y, a0.z, a0.w};
  float ta1[4] = {a1.x, a1.y, a1.z, a1.w};
  float tb0[4] = {b0.x, b0.y, b0.z, b0.w};
  float tb1[4] = {b1.x, b1.y, b1.z, b1.w};
#pragma unroll
  for (int i = 0; i < 4; ++i) {
    int j = j0 + i;
    int g1 = (h2 >> 3) ^ (j & 7);
    us32[(j * 256 + (g1 << 4) + ((2 * h2) & 15)) >> 2] = pack2(ta0[i], ta1[i]);
    int hb = h2 + 64;
    int g2 = (hb >> 3) ^ (j & 7);
    us32[(j * 256 + (g2 << 4) + ((2 * hb) & 15)) >> 2] = pack2(tb0[i], tb1[i]);
  }
}

// Bu = B_bar @ u_tile via MFMA; writes packed bf16 (re,im) to bu32[p<<5 | (j^perm(p))]
__device__ __forceinline__ void compute_bu(const unsigned* us32,
                                           const bf16x8* __restrict__ Bfr,
                                           const bf16x8* __restrict__ Bfi,
                                           unsigned* bu32, int t) {
  int lane = t & 63, w = t >> 6, q = lane >> 4, ln = lane & 15;
  f32x4 zz = {0.f, 0.f, 0.f, 0.f};
  f32x4 aR[4][2], aI[4][2];
#pragma unroll
  for (int mt = 0; mt < 4; ++mt)
#pragma unroll
    for (int n = 0; n < 2; ++n) { aR[mt][n] = zz; aI[mt][n] = zz; }

#pragma unroll
  for (int ks = 0; ks < 4; ++ks) {
    bf16x8 ubf[2];
#pragma unroll
    for (int n = 0; n < 2; ++n) {
      int j = 16 * n + ln;
      int g = (4 * ks + q) ^ (j & 7);
      ubf[n] = *(const bf16x8*)((const char*)us32 + j * 256 + g * 16);
    }
#pragma unroll
    for (int mt = 0; mt < 4; ++mt) {
      int tI = ks * 16 + w * 4 + mt;
      bf16x8 ar = Bfr[tI * 64 + lane];
      bf16x8 ai = Bfi[tI * 64 + lane];
#pragma unroll
      for (int n = 0; n < 2; ++n) {
        aR[mt][n] = MFMA16(ar, ubf[n], aR[mt][n]);
        aI[mt][n] = MFMA16(ai, ubf[n], aI[mt][n]);
      }
    }
  }
#pragma unroll
  for (int mt = 0; mt < 4; ++mt)
#pragma unroll
    for (int n = 0; n < 2; ++n)
#pragma unroll
      for (int r = 0; r < 4; ++r) {
        int p = w * 64 + mt * 16 + q * 4 + r;
        int j = 16 * n + ln;
        bu32[(p << 5) | (j ^ bperm(p))] = pack2(aR[mt][n][r], aI[mt][n][r]);
      }
}

// ---------------- kernel 1: per-chunk state contribution E ----------------
__global__ __launch_bounds__(256, 4) void k_chunk(
    const float* __restrict__ u, const float* __restrict__ lre,
    const float* __restrict__ lim, const bf16x8* __restrict__ Bfr,
    const bf16x8* __restrict__ Bfi, float2* __restrict__ E) {
  int bc = blockIdx.x;
  int b = bc >> 8, c = bc & 255;
  __shared__ __align__(16) unsigned char smem[8192 + 32768];  // 40960 = 160K/4
  unsigned* us32 = (unsigned*)smem;
  unsigned* bu32 = (unsigned*)(smem + 8192);
  int t = threadIdx.x;

  stage_u(u + (size_t)b * Hd * Ld + c * LC, us32, t);
  __syncthreads();
  compute_bu(us32, Bfr, Bfi, bu32, t);
  __syncthreads();

  int p = t;
  int pm = bperm(p);
  float ax = lre[p], ay = lim[p];
  float xr = 0.f, xi = 0.f;
#pragma unroll
  for (int j = 0; j < LC; ++j) {
    unsigned v = bu32[(p << 5) | (j ^ pm)];
    float sr = xr + bflo(v), si = xi + bfhi(v);
    xr = ax * sr - ay * si;
    xi = ax * si + ay * sr;
  }
  E[(size_t)bc * Pd + p] = make_float2(xr, xi);
}

// ---------------- kernel 2: parallel prefix scan over chunks ----------------
// 8 threads per (b,p); each owns a run of 32 chunks. Local exclusive scan in
// regs, Hillis-Steele over the 8 run totals via shfl (uniform multiplier S=a^32
// per step distance), then seeded writeback. E[c] <- incoming state of chunk c.
__global__ __launch_bounds__(256) void k_scan(const float* __restrict__ lre,
                                              const float* __restrict__ lim,
                                              float2* __restrict__ E) {
  int g = blockIdx.x * 256 + threadIdx.x;  // 0..16383
  int b = g >> 11;
  int p = (g >> 3) & 255;
  int rq = g & 7;
  float ax = lre[p], ay = lim[p];
  float sx = ax, sy = ay;
#pragma unroll
  for (int k = 0; k < 5; ++k) {  // s = a^32
    float nx = sx * sx - sy * sy, ny = 2.f * sx * sy;
    sx = nx; sy = ny;
  }
  size_t base = ((size_t)(b * NC + rq * 32)) * Pd + p;
  float2 pre[32];
  float cr = 0.f, ci = 0.f;
#pragma unroll 8
  for (int i = 0; i < 32; ++i) {
    float2 e = E[base + (size_t)i * Pd];
    pre[i] = make_float2(cr, ci);
    float nx = sx * cr - sy * ci + e.x;
    float ny = sx * ci + sy * cr + e.y;
    cr = nx; ci = ny;
  }
  // run multiplier S = s^32
  float Sx = sx, Sy = sy;
#pragma unroll
  for (int k = 0; k < 5; ++k) {
    float nx = Sx * Sx - Sy * Sy, ny = 2.f * Sx * Sy;
    Sx = nx; Sy = ny;
  }
  // inclusive Hillis-Steele across the 8-lane group
  float Vx = cr, Vy = ci;
  float Mx = Sx, My = Sy;  // S^d
#pragma unroll
  for (int d = 1; d < 8; d <<= 1) {
    float ux = __shfl_up(Vx, d, 8);
    float uy = __shfl_up(Vy, d, 8);
    if (rq >= d) {
      Vx += Mx * ux - My * uy;
      Vy += Mx * uy + My * ux;
    }
    float nx = Mx * Mx - My * My, ny = 2.f * Mx * My;
    Mx = nx; My = ny;
  }
  // exclusive: carry entering this run
  float Cx = __shfl_up(Vx, 1, 8);
  float Cy = __shfl_up(Vy, 1, 8);
  if (rq == 0) { Cx = 0.f; Cy = 0.f; }
  // writeback: out_i = pre_i + s^i * C
  float tx = 1.f, ty = 0.f;
#pragma unroll 8
  for (int i = 0; i < 32; ++i) {
    float ox = pre[i].x + tx * Cx - ty * Cy;
    float oy = pre[i].y + tx * Cy + ty * Cx;
    E[base + (size_t)i * Pd] = make_float2(ox, oy);
    float nx = tx * sx - ty * sy, ny = tx * sy + ty * sx;
    tx = nx; ty = ny;
  }
}

// ---------------- kernel 3: main fused kernel ----------------
__global__ __launch_bounds__(256, 4) void k_main(
    const float* __restrict__ u, const float* __restrict__ lre,
    const float* __restrict__ lim, const bf16x8* __restrict__ Bfr,
    const bf16x8* __restrict__ Bfi, const bf16x8* __restrict__ Cf,
    const bf16x8* __restrict__ Df, const float2* __restrict__ E,
    float* __restrict__ out) {
  int bc = blockIdx.x;
  int b = bc >> 8, c = bc & 255;
  __shared__ __align__(16) unsigned char smem[8192 + 32768];  // 40960 = 160K/4
  unsigned* us32 = (unsigned*)smem;
  unsigned* bu32 = (unsigned*)(smem + 8192);
  unsigned* xs32 = bu32;  // alias: bu dead after scan reads
  int t = threadIdx.x;
  int lane = t & 63, w = t >> 6, q = lane >> 4, ln = lane & 15;

  stage_u(u + (size_t)b * Hd * Ld + c * LC, us32, t);
  __syncthreads();
  compute_bu(us32, Bfr, Bfi, bu32, t);
  __syncthreads();

  // ---- scan: thread p owns row p; buffer bu row in regs so xs can alias ----
  int p = t;
  int pm = bperm(p);
  unsigned v[LC];
#pragma unroll
  for (int j = 0; j < LC; ++j) v[j] = bu32[(p << 5) | (j ^ pm)];
  float2 xin = E[(size_t)bc * Pd + p];
  __syncthreads();  // all bu reads done before xs overwrites

  {
    float ax = lre[p], ay = lim[p];
    float xr = xin.x, xi = xin.y;
#pragma unroll
    for (int j = 0; j < LC; ++j) {
      float sr = xr + bflo(v[j]), si = xi + bfhi(v[j]);
      xr = ax * sr - ay * si;
      xi = ax * si + ay * sr;
      xs32[j * 256 + ((((p >> 2) ^ (j & 7)) << 2) + (p & 3))] = pack2(xr, xi);
    }
  }
  __syncthreads();

  // ---- projection: y = [Cre | -Cim] @ xs_interleaved + D @ u ----
  f32x4 zz = {0.f, 0.f, 0.f, 0.f};
  f32x4 acc[2][2] = {{zz, zz}, {zz, zz}};
#pragma unroll
  for (int ks = 0; ks < 16; ++ks) {
    bf16x8 xb[2];
#pragma unroll
    for (int n = 0; n < 2; ++n) {
      int j = 16 * n + ln;
      int g = (4 * ks + q) ^ (j & 7);
      xb[n] = *(const bf16x8*)((const char*)xs32 + j * 1024 + g * 16);
    }
#pragma unroll
    for (int mt = 0; mt < 2; ++mt) {
      bf16x8 cf = Cf[(ks * 8 + w * 2 + mt) * 64 + lane];
#pragma unroll
      for (int n = 0; n < 2; ++n) acc[mt][n] = MFMA16(cf, xb[n], acc[mt][n]);
    }
  }
#pragma unroll
  for (int ks = 0; ks < 4; ++ks) {
    bf16x8 ubf[2];
#pragma unroll
    for (int n = 0; n < 2; ++n) {
      int j = 16 * n + ln;
      int g = (4 * ks + q) ^ (j & 7);
      ubf[n] = *(const bf16x8*)((const char*)us32 + j * 256 + g * 16);
    }
#pragma unroll
    for (int mt = 0; mt < 2; ++mt) {
      bf16x8 df = Df[(ks * 8 + w * 2 + mt) * 64 + lane];
#pragma unroll
      for (int n = 0; n < 2; ++n) acc[mt][n] = MFMA16(df, ubf[n], acc[mt][n]);
    }
  }

  // ---- GELU (sigmoid form, |err| <= ~0.02 abs) + store ----
#pragma unroll
  for (int mt = 0; mt < 2; ++mt)
#pragma unroll
    for (int n = 0; n < 2; ++n)
#pragma unroll
      for (int r = 0; r < 4; ++r) {
        int o = w * 32 + mt * 16 + q * 4 + r;
        int l = c * LC + 16 * n + ln;
        float vy = acc[mt][n][r];
        float e2 = __builtin_amdgcn_exp2f(-2.4554670f * vy);  // exp(-1.702 v)
        float gy = vy * __builtin_amdgcn_rcpf(1.0f + e2);
        out[((size_t)(b * Hd + o)) * Ld + l] = gy;
      }
}

// ---------------- launch ----------------
extern "C" void kernel_launch(void* const* d_in, const int* in_sizes, int n_in,
                              void* d_out, int out_size, void* d_ws, size_t ws_size,
                              hipStream_t stream) {
  const float* u   = (const float*)d_in[0];
  const float* lre = (const float*)d_in[1];
  const float* lim = (const float*)d_in[2];
  const float* Bre = (const float*)d_in[3];
  const float* Bim = (const float*)d_in[4];
  const float* Cre = (const float*)d_in[5];
  const float* Cim = (const float*)d_in[6];
  const float* Dm  = (const float*)d_in[7];
  float* out = (float*)d_out;

  char* ws = (char*)d_ws;
  bf16x8* Bfr = (bf16x8*)(ws);                 // 64 KB
  bf16x8* Bfi = (bf16x8*)(ws + 65536);         // 64 KB
  bf16x8* Cf  = (bf16x8*)(ws + 131072);        // 128 KB
  bf16x8* Df  = (bf16x8*)(ws + 262144);        // 32 KB
  float2* E   = (float2*)(ws + (1 << 20));     // 4 MB

  k_prep<<<56, 256, 0, stream>>>(Bre, Bim, Cre, Cim, Dm, Bfr, Bfi, Cf, Df);
  k_chunk<<<Bn * NC, 256, 0, stream>>>(u, lre, lim, Bfr, Bfi, E);
  k_scan<<<64, 256, 0, stream>>>(lre, lim, E);
  k_main<<<Bn * NC, 256, 0, stream>>>(u, lre, lim, Bfr, Bfi, Cf, Df, E, out);
}